// Round 9
// baseline (187.389 us; speedup 1.0000x reference)
//
#include <hip/hip_runtime.h>

// ---------------------------------------------------------------------------
// GCN 2-layer forward. Build: atomic-free bucket binning -> per-bucket LDS
// reorder into CSR (offs + ushort adj). Smooth: wave-per-node CSR gather.
// GEMM1 via split-bf16 MFMA (hi+lo, 3-term) -- f32-level accuracy.
// ---------------------------------------------------------------------------

#define B1 256          // histogram / scatter blocks
#define BUCK_SHIFT 6    // 64 nodes per bucket
#define MAXBUCK 4096    // LDS hist cap
#define RCAP 8192       // reorder LDS staging entries (16KB)

typedef float f32x4 __attribute__((ext_vector_type(4)));
typedef short bf16x8 __attribute__((ext_vector_type(8)));

union Frag { unsigned int u[4]; bf16x8 v; };

__device__ __forceinline__ unsigned int cvt_pk_bf16(float a, float b) {
    unsigned int r;
    asm("v_cvt_pk_bf16_f32 %0, %1, %2" : "=v"(r) : "v"(a), "v"(b));
    return r;  // low16 = bf16(a), high16 = bf16(b), RNE
}

__global__ __launch_bounds__(256) void k_hist(const int* __restrict__ src,
                                              const int* __restrict__ dst,
                                              int* __restrict__ hist,
                                              int E, int nbuck, int chunk) {
    __shared__ int lh[MAXBUCK];
    for (int i = threadIdx.x; i < nbuck; i += 256) lh[i] = 0;
    __syncthreads();
    int e0 = blockIdx.x * chunk;
    int e1 = min(e0 + chunk, E);
    for (int e = e0 + threadIdx.x; e < e1; e += 256) {
        atomicAdd(&lh[src[e] >> BUCK_SHIFT], 1);
        atomicAdd(&lh[dst[e] >> BUCK_SHIFT], 1);
    }
    __syncthreads();
    for (int i = threadIdx.x; i < nbuck; i += 256)
        hist[i * B1 + blockIdx.x] = lh[i];
}

__global__ __launch_bounds__(256) void k_block_sum(const int* __restrict__ d,
                                                   int* __restrict__ bsum, int n) {
    __shared__ int s[256];
    int i = blockIdx.x * 256 + threadIdx.x;
    s[threadIdx.x] = (i < n) ? d[i] : 0;
    __syncthreads();
    for (int w = 128; w > 0; w >>= 1) {
        if (threadIdx.x < w) s[threadIdx.x] += s[threadIdx.x + w];
        __syncthreads();
    }
    if (threadIdx.x == 0) bsum[blockIdx.x] = s[0];
}

__global__ __launch_bounds__(1024) void k_scan_single(int* __restrict__ d, int n) {
    __shared__ int s[2][1024];
    int t = threadIdx.x;
    int per = (n + 1023) >> 10;
    int lo = t * per, hi = min(lo + per, n);
    int sum = 0;
    for (int i = lo; i < hi; ++i) sum += d[i];
    s[0][t] = sum;
    __syncthreads();
    int pin = 0;
    for (int w = 1; w < 1024; w <<= 1) {
        int po = pin ^ 1;
        int v = s[pin][t];
        if (t >= w) v += s[pin][t - w];
        s[po][t] = v;
        __syncthreads();
        pin = po;
    }
    int base = s[pin][t] - sum;  // exclusive
    for (int i = lo; i < hi; ++i) { int v = d[i]; d[i] = base; base += v; }
}

__global__ __launch_bounds__(256) void k_scan_block(int* __restrict__ data,
                                                    const int* __restrict__ bases,
                                                    int n) {
    __shared__ int s[2][256];
    int t = threadIdx.x;
    int i = blockIdx.x * 256 + t;
    int v = (i < n) ? data[i] : 0;
    s[0][t] = v;
    __syncthreads();
    int pin = 0;
    for (int w = 1; w < 256; w <<= 1) {
        int po = pin ^ 1;
        int val = s[pin][t];
        if (t >= w) val += s[pin][t - w];
        s[po][t] = val;
        __syncthreads();
        pin = po;
    }
    if (i < n) data[i] = s[pin][t] - v + bases[blockIdx.x];
}

__global__ __launch_bounds__(256) void k_scatter(const int* __restrict__ src,
                                                 const int* __restrict__ dst,
                                                 const int* __restrict__ scan,
                                                 unsigned int* __restrict__ binned,
                                                 int E, int nbuck, int chunk) {
    __shared__ int cur[MAXBUCK];
    for (int i = threadIdx.x; i < nbuck; i += 256)
        cur[i] = scan[i * B1 + blockIdx.x];
    __syncthreads();
    int e0 = blockIdx.x * chunk;
    int e1 = min(e0 + chunk, E);
    for (int e = e0 + threadIdx.x; e < e1; e += 256) {
        unsigned int s = (unsigned int)src[e];
        unsigned int d = (unsigned int)dst[e];
        int p = atomicAdd(&cur[s >> BUCK_SHIFT], 1);
        binned[p] = (s << 16) | d;
        int q = atomicAdd(&cur[d >> BUCK_SHIFT], 1);
        binned[q] = (d << 16) | s;
    }
}

__global__ __launch_bounds__(256) void k_reorder(const unsigned int* __restrict__ binned,
                                                 const int* __restrict__ scan,
                                                 unsigned short* __restrict__ adj,
                                                 int* __restrict__ offs,
                                                 float* __restrict__ dis,
                                                 int N, int nbuck, int M) {
    __shared__ int cnt[64];
    __shared__ int cur[64];
    __shared__ unsigned short stage[RCAP];
    int b = blockIdx.x;
    int start = scan[b * B1];
    int end = (b + 1 < nbuck) ? scan[(b + 1) * B1] : M;
    int len = end - start;
    if (threadIdx.x < 64) cnt[threadIdx.x] = 0;
    __syncthreads();
    for (int i = start + threadIdx.x; i < end; i += 256)
        atomicAdd(&cnt[(binned[i] >> 16) & 63], 1);
    __syncthreads();
    if (threadIdx.x == 0) {
        int run = 0;
        for (int l = 0; l < 64; ++l) { cur[l] = run; run += cnt[l]; }
    }
    __syncthreads();
    if (threadIdx.x < 64) {
        int node = (b << BUCK_SHIFT) + threadIdx.x;
        if (node < N) {
            offs[node] = start + cur[threadIdx.x];
            dis[node]  = rsqrtf(1.0f + (float)cnt[threadIdx.x]);
        }
    }
    __syncthreads();
    if (len <= RCAP) {
        for (int i = start + threadIdx.x; i < end; i += 256) {
            unsigned int v = binned[i];
            int nl = (v >> 16) & 63;
            int p = atomicAdd(&cur[nl], 1);
            stage[p] = (unsigned short)(v & 0xffffu);
        }
        __syncthreads();
        for (int i = threadIdx.x; i < len; i += 256)
            adj[start + i] = stage[i];
    } else {
        for (int i = start + threadIdx.x; i < end; i += 256) {
            unsigned int v = binned[i];
            int nl = (v >> 16) & 63;
            int p = atomicAdd(&cur[nl], 1);
            adj[start + p] = (unsigned short)(v & 0xffffu);
        }
    }
}

// ---------------------------------------------------------------------------
// GEMM1 via MFMA: hs[N][64] = (X[N][128] @ W1[128][64] + b1) * dis[row].
// Split-bf16: x = hi + lo; D = Ahi*Bhi + Alo*Bhi + Ahi*Blo (lo*lo dropped).
// Wave: 32 rows (2 x 16-row tiles) x 64 cols (4 x 16-col tiles).
// Block: 4 waves = 128 rows. W1 in LDS transposed [col][k], K-stride 136.
// ---------------------------------------------------------------------------
#define WK 136  // padded K stride (ushorts): 272B -> bank stride 4, 2-way free

__device__ __forceinline__ bf16x8 ld_frag(const unsigned short* p) {
    uint4 t = *reinterpret_cast<const uint4*>(p);
    Frag f; f.u[0] = t.x; f.u[1] = t.y; f.u[2] = t.z; f.u[3] = t.w;
    return f.v;
}

__device__ __forceinline__ void make_frags(const float4 a, const float4 b,
                                           bf16x8& hi8, bf16x8& lo8) {
    Frag hi, lo;
    hi.u[0] = cvt_pk_bf16(a.x, a.y);
    hi.u[1] = cvt_pk_bf16(a.z, a.w);
    hi.u[2] = cvt_pk_bf16(b.x, b.y);
    hi.u[3] = cvt_pk_bf16(b.z, b.w);
    lo.u[0] = cvt_pk_bf16(a.x - __uint_as_float(hi.u[0] << 16),
                          a.y - __uint_as_float(hi.u[0] & 0xffff0000u));
    lo.u[1] = cvt_pk_bf16(a.z - __uint_as_float(hi.u[1] << 16),
                          a.w - __uint_as_float(hi.u[1] & 0xffff0000u));
    lo.u[2] = cvt_pk_bf16(b.x - __uint_as_float(hi.u[2] << 16),
                          b.y - __uint_as_float(hi.u[2] & 0xffff0000u));
    lo.u[3] = cvt_pk_bf16(b.z - __uint_as_float(hi.u[3] << 16),
                          b.w - __uint_as_float(hi.u[3] & 0xffff0000u));
    hi8 = hi.v; lo8 = lo.v;
}

__global__ __launch_bounds__(256) void k_gemm1_mfma(const float* __restrict__ X,
                                                    const float* __restrict__ W1,
                                                    const float* __restrict__ b1,
                                                    const float* __restrict__ dis,
                                                    float* __restrict__ hs, int N) {
    __shared__ unsigned short sWhi[64 * WK];
    __shared__ unsigned short sWlo[64 * WK];
    // Stage W1 transposed: consecutive threads take consecutive k (same col)
    // -> LDS writes conflict-free; global reads strided but W1 is 32KB (L2).
    for (int i = threadIdx.x; i < 128 * 64; i += 256) {
        int c = i >> 7;      // 0..63
        int k = i & 127;     // 0..127
        float w = W1[(size_t)k * 64 + c];
        unsigned int hb = cvt_pk_bf16(w, 0.0f) & 0xffffu;
        float hf = __uint_as_float(hb << 16);
        unsigned int lb = cvt_pk_bf16(w - hf, 0.0f) & 0xffffu;
        sWhi[c * WK + k] = (unsigned short)hb;
        sWlo[c * WK + k] = (unsigned short)lb;
    }
    __syncthreads();

    const int lane = threadIdx.x & 63;
    const int wid  = threadIdx.x >> 6;
    const int ridx = lane & 15;   // row within 16-tile (A), col within 16 (B/C)
    const int kgrp = lane >> 4;   // 0..3 : k-octet group
    const int r0 = blockIdx.x * 128 + wid * 32;

    f32x4 acc[2][4] = {};

    #pragma unroll
    for (int ks = 0; ks < 4; ++ks) {
        const int ka = ks * 32 + kgrp * 8;
        int ra0 = min(r0 + ridx, N - 1);
        int ra1 = min(r0 + 16 + ridx, N - 1);
        const float4* pa0 = (const float4*)(X + (size_t)ra0 * 128 + ka);
        const float4* pa1 = (const float4*)(X + (size_t)ra1 * 128 + ka);
        float4 a0a = pa0[0], a0b = pa0[1];
        float4 a1a = pa1[0], a1b = pa1[1];
        bf16x8 a0hi, a0lo, a1hi, a1lo;
        make_frags(a0a, a0b, a0hi, a0lo);
        make_frags(a1a, a1b, a1hi, a1lo);
        #pragma unroll
        for (int ct = 0; ct < 4; ++ct) {
            const int cbase = (ct * 16 + ridx) * WK + ka;
            bf16x8 bh = ld_frag(sWhi + cbase);
            bf16x8 bl = ld_frag(sWlo + cbase);
            acc[0][ct] = __builtin_amdgcn_mfma_f32_16x16x32_bf16(a0hi, bh, acc[0][ct], 0, 0, 0);
            acc[0][ct] = __builtin_amdgcn_mfma_f32_16x16x32_bf16(a0lo, bh, acc[0][ct], 0, 0, 0);
            acc[0][ct] = __builtin_amdgcn_mfma_f32_16x16x32_bf16(a0hi, bl, acc[0][ct], 0, 0, 0);
            acc[1][ct] = __builtin_amdgcn_mfma_f32_16x16x32_bf16(a1hi, bh, acc[1][ct], 0, 0, 0);
            acc[1][ct] = __builtin_amdgcn_mfma_f32_16x16x32_bf16(a1lo, bh, acc[1][ct], 0, 0, 0);
            acc[1][ct] = __builtin_amdgcn_mfma_f32_16x16x32_bf16(a1hi, bl, acc[1][ct], 0, 0, 0);
        }
    }

    float bias[4];
    #pragma unroll
    for (int ct = 0; ct < 4; ++ct) bias[ct] = b1[ct * 16 + ridx];

    #pragma unroll
    for (int rt = 0; rt < 2; ++rt) {
        int rb = r0 + rt * 16 + kgrp * 4;
        #pragma unroll
        for (int reg = 0; reg < 4; ++reg) {
            int r = rb + reg;
            if (r < N) {
                float dv = dis[r];
                #pragma unroll
                for (int ct = 0; ct < 4; ++ct)
                    hs[(size_t)r * 64 + ct * 16 + ridx] = (acc[rt][ct][reg] + bias[ct]) * dv;
            }
        }
    }
}

// out1[i][c] = relu(dis[i]*(hs[i][c] + sum_j hs[j][c])); wave per node.
__global__ __launch_bounds__(256) void k_gather64(const float* __restrict__ hs,
                                                  const unsigned short* __restrict__ adj,
                                                  const int* __restrict__ offs,
                                                  const float* __restrict__ dis,
                                                  float* __restrict__ out, int N, int M) {
    int node = (blockIdx.x * 256 + threadIdx.x) >> 6;
    int c = threadIdx.x & 63;
    if (node >= N) return;
    int k   = offs[node];
    int end = (node + 1 < N) ? offs[node + 1] : M;
    float d = dis[node];
    float acc = hs[(size_t)node * 64 + c];
    for (; k + 8 <= end; k += 8) {
        int j0 = adj[k + 0], j1 = adj[k + 1], j2 = adj[k + 2], j3 = adj[k + 3];
        int j4 = adj[k + 4], j5 = adj[k + 5], j6 = adj[k + 6], j7 = adj[k + 7];
        float v0 = hs[(size_t)j0 * 64 + c];
        float v1 = hs[(size_t)j1 * 64 + c];
        float v2 = hs[(size_t)j2 * 64 + c];
        float v3 = hs[(size_t)j3 * 64 + c];
        float v4 = hs[(size_t)j4 * 64 + c];
        float v5 = hs[(size_t)j5 * 64 + c];
        float v6 = hs[(size_t)j6 * 64 + c];
        float v7 = hs[(size_t)j7 * 64 + c];
        acc += ((v0 + v1) + (v2 + v3)) + ((v4 + v5) + (v6 + v7));
    }
    for (; k < end; ++k)
        acc += hs[(size_t)adj[k] * 64 + c];
    out[(size_t)node * 64 + c] = fmaxf(d * acc, 0.0f);
}

// h2s[N][40] = (out1[N][64] @ W2[64][40] + b2) * dis[row]
__global__ __launch_bounds__(256) void k_gemm2(const float* __restrict__ A,
                                               const float* __restrict__ W2,
                                               const float* __restrict__ b2,
                                               const float* __restrict__ dis,
                                               float* __restrict__ h2s, int n40) {
    __shared__ float sW[64 * 40];
    __shared__ float sb[40];
    for (int i = threadIdx.x; i < 64 * 40; i += 256) sW[i] = W2[i];
    if (threadIdx.x < 40) sb[threadIdx.x] = b2[threadIdx.x];
    __syncthreads();
    int t = blockIdx.x * 256 + threadIdx.x;
    if (t >= n40) return;
    int row = t / 40;
    int col = t - row * 40;
    const float4* a = (const float4*)(A + (size_t)row * 64);
    float acc = sb[col];
    #pragma unroll
    for (int k4 = 0; k4 < 16; ++k4) {
        float4 v = a[k4];
        const float* w = &sW[k4 * 4 * 40 + col];
        acc += v.x * w[0] + v.y * w[40] + v.z * w[80] + v.w * w[120];
    }
    h2s[t] = acc * dis[row];
}

// out2[i][c] = dis[i]*(h2s[i][c] + sum_j h2s[j][c]); wave per node, c<40.
__global__ __launch_bounds__(256) void k_gather40(const float* __restrict__ h2s,
                                                  const unsigned short* __restrict__ adj,
                                                  const int* __restrict__ offs,
                                                  const float* __restrict__ dis,
                                                  float* __restrict__ out, int N, int M) {
    int node = (blockIdx.x * 256 + threadIdx.x) >> 6;
    int c = threadIdx.x & 63;
    if (node >= N || c >= 40) return;
    int k   = offs[node];
    int end = (node + 1 < N) ? offs[node + 1] : M;
    float d = dis[node];
    float acc = h2s[(size_t)node * 40 + c];
    for (; k + 8 <= end; k += 8) {
        int j0 = adj[k + 0], j1 = adj[k + 1], j2 = adj[k + 2], j3 = adj[k + 3];
        int j4 = adj[k + 4], j5 = adj[k + 5], j6 = adj[k + 6], j7 = adj[k + 7];
        float v0 = h2s[(size_t)j0 * 40 + c];
        float v1 = h2s[(size_t)j1 * 40 + c];
        float v2 = h2s[(size_t)j2 * 40 + c];
        float v3 = h2s[(size_t)j3 * 40 + c];
        float v4 = h2s[(size_t)j4 * 40 + c];
        float v5 = h2s[(size_t)j5 * 40 + c];
        float v6 = h2s[(size_t)j6 * 40 + c];
        float v7 = h2s[(size_t)j7 * 40 + c];
        acc += ((v0 + v1) + (v2 + v3)) + ((v4 + v5) + (v6 + v7));
    }
    for (; k < end; ++k)
        acc += h2s[(size_t)adj[k] * 40 + c];
    out[(size_t)node * 40 + c] = d * acc;
}

extern "C" void kernel_launch(void* const* d_in, const int* in_sizes, int n_in,
                              void* d_out, int out_size, void* d_ws, size_t ws_size,
                              hipStream_t stream) {
    const float* X  = (const float*)d_in[0];
    const float* W1 = (const float*)d_in[1];
    const float* b1 = (const float*)d_in[2];
    const float* W2 = (const float*)d_in[3];
    const float* b2 = (const float*)d_in[4];
    const int*   ei = (const int*)d_in[5];

    const int Chid = in_sizes[2];            // 64
    const int Cin  = in_sizes[1] / Chid;     // 128
    const int N    = in_sizes[0] / Cin;      // 50000
    const int E    = in_sizes[5] / 2;        // 800000

    const int* src = ei;
    const int* dst = ei + E;

    const int M = 2 * E;                        // 1.6M entries
    const int nbuck = (N + 63) >> BUCK_SHIFT;   // 782
    const int histLen = nbuck * B1;             // 200192
    const int chunk = (E + B1 - 1) / B1;        // 3125
    const int nb2 = (histLen + 255) / 256;      // 782

    // ---- workspace layout (binned and hs overlap: binned dead after reorder)
    auto align256 = [](size_t x) { return (x + 255) & ~(size_t)255; };
    char* p = (char*)d_ws;
    int*   hist = (int*)p;   p += align256((size_t)histLen * 4);
    int*   bsum = (int*)p;   p += align256((size_t)nb2 * 4);
    float* dis  = (float*)p; p += align256((size_t)N * 4);
    int*   offs = (int*)p;   p += align256((size_t)N * 4);
    unsigned short* adj = (unsigned short*)p; p += align256((size_t)M * 2);
    unsigned int* binned = (unsigned int*)p;        // M uints (6.4MB) ...
    float* hs  = (float*)p;                          // ... reused as N*64 floats
    float* h2s = hs;                                 // reused again after out1

    float* out1 = (float*)d_out;             // N*64
    float* out2 = out1 + (size_t)N * 64;     // N*40

    k_hist<<<B1, 256, 0, stream>>>(src, dst, hist, E, nbuck, chunk);
    k_block_sum<<<nb2, 256, 0, stream>>>(hist, bsum, histLen);
    k_scan_single<<<1, 1024, 0, stream>>>(bsum, nb2);
    k_scan_block<<<nb2, 256, 0, stream>>>(hist, bsum, histLen);
    k_scatter<<<B1, 256, 0, stream>>>(src, dst, hist, binned, E, nbuck, chunk);
    k_reorder<<<nbuck, 256, 0, stream>>>(binned, hist, adj, offs, dis, N, nbuck, M);

    k_gemm1_mfma<<<(N + 127) / 128, 256, 0, stream>>>(X, W1, b1, dis, hs, N);
    k_gather64<<<(N + 3) / 4, 256, 0, stream>>>(hs, adj, offs, dis, out1, N, M);

    int n40 = N * 40;
    k_gemm2<<<(n40 + 255) / 256, 256, 0, stream>>>(out1, W2, b2, dis, h2s, n40);
    k_gather40<<<(N + 3) / 4, 256, 0, stream>>>(h2s, adj, offs, dis, out2, N, M);
}

// Round 10
// 161.669 us; speedup vs baseline: 1.1591x; 1.1591x over previous
//
#include <hip/hip_runtime.h>

// ---------------------------------------------------------------------------
// GCN 2-layer forward. Build: atomic-free bucket binning -> per-bucket LDS
// reorder into CSR (offs + ushort adj). Smooth: wave-per-node CSR gather on
// bf16-packed feature rows (halves L2-miss traffic; h2s fits per-XCD L2).
// GEMM1 via split-bf16 MFMA (hi+lo, 3-term) -- f32-level accuracy.
// ---------------------------------------------------------------------------

#define B1 256          // histogram / scatter blocks
#define BUCK_SHIFT 6    // 64 nodes per bucket
#define MAXBUCK 4096    // LDS hist cap
#define RCAP 8192       // reorder LDS staging entries (16KB)

typedef float f32x4 __attribute__((ext_vector_type(4)));
typedef short bf16x8 __attribute__((ext_vector_type(8)));

union Frag { unsigned int u[4]; bf16x8 v; };

__device__ __forceinline__ unsigned int cvt_pk_bf16(float a, float b) {
    unsigned int r;
    asm("v_cvt_pk_bf16_f32 %0, %1, %2" : "=v"(r) : "v"(a), "v"(b));
    return r;  // low16 = bf16(a), high16 = bf16(b), RNE
}

__device__ __forceinline__ float bf_lo(unsigned int u) {
    return __uint_as_float(u << 16);
}
__device__ __forceinline__ float bf_hi(unsigned int u) {
    return __uint_as_float(u & 0xffff0000u);
}

__global__ __launch_bounds__(256) void k_hist(const int* __restrict__ src,
                                              const int* __restrict__ dst,
                                              int* __restrict__ hist,
                                              int E, int nbuck, int chunk) {
    __shared__ int lh[MAXBUCK];
    for (int i = threadIdx.x; i < nbuck; i += 256) lh[i] = 0;
    __syncthreads();
    int e0 = blockIdx.x * chunk;
    int e1 = min(e0 + chunk, E);
    for (int e = e0 + threadIdx.x; e < e1; e += 256) {
        atomicAdd(&lh[src[e] >> BUCK_SHIFT], 1);
        atomicAdd(&lh[dst[e] >> BUCK_SHIFT], 1);
    }
    __syncthreads();
    for (int i = threadIdx.x; i < nbuck; i += 256)
        hist[i * B1 + blockIdx.x] = lh[i];
}

__global__ __launch_bounds__(256) void k_block_sum(const int* __restrict__ d,
                                                   int* __restrict__ bsum, int n) {
    __shared__ int s[256];
    int i = blockIdx.x * 256 + threadIdx.x;
    s[threadIdx.x] = (i < n) ? d[i] : 0;
    __syncthreads();
    for (int w = 128; w > 0; w >>= 1) {
        if (threadIdx.x < w) s[threadIdx.x] += s[threadIdx.x + w];
        __syncthreads();
    }
    if (threadIdx.x == 0) bsum[blockIdx.x] = s[0];
}

__global__ __launch_bounds__(1024) void k_scan_single(int* __restrict__ d, int n) {
    __shared__ int s[2][1024];
    int t = threadIdx.x;
    int per = (n + 1023) >> 10;
    int lo = t * per, hi = min(lo + per, n);
    int sum = 0;
    for (int i = lo; i < hi; ++i) sum += d[i];
    s[0][t] = sum;
    __syncthreads();
    int pin = 0;
    for (int w = 1; w < 1024; w <<= 1) {
        int po = pin ^ 1;
        int v = s[pin][t];
        if (t >= w) v += s[pin][t - w];
        s[po][t] = v;
        __syncthreads();
        pin = po;
    }
    int base = s[pin][t] - sum;  // exclusive
    for (int i = lo; i < hi; ++i) { int v = d[i]; d[i] = base; base += v; }
}

__global__ __launch_bounds__(256) void k_scan_block(int* __restrict__ data,
                                                    const int* __restrict__ bases,
                                                    int n) {
    __shared__ int s[2][256];
    int t = threadIdx.x;
    int i = blockIdx.x * 256 + t;
    int v = (i < n) ? data[i] : 0;
    s[0][t] = v;
    __syncthreads();
    int pin = 0;
    for (int w = 1; w < 256; w <<= 1) {
        int po = pin ^ 1;
        int val = s[pin][t];
        if (t >= w) val += s[pin][t - w];
        s[po][t] = val;
        __syncthreads();
        pin = po;
    }
    if (i < n) data[i] = s[pin][t] - v + bases[blockIdx.x];
}

__global__ __launch_bounds__(256) void k_scatter(const int* __restrict__ src,
                                                 const int* __restrict__ dst,
                                                 const int* __restrict__ scan,
                                                 unsigned int* __restrict__ binned,
                                                 int E, int nbuck, int chunk) {
    __shared__ int cur[MAXBUCK];
    for (int i = threadIdx.x; i < nbuck; i += 256)
        cur[i] = scan[i * B1 + blockIdx.x];
    __syncthreads();
    int e0 = blockIdx.x * chunk;
    int e1 = min(e0 + chunk, E);
    for (int e = e0 + threadIdx.x; e < e1; e += 256) {
        unsigned int s = (unsigned int)src[e];
        unsigned int d = (unsigned int)dst[e];
        int p = atomicAdd(&cur[s >> BUCK_SHIFT], 1);
        binned[p] = (s << 16) | d;
        int q = atomicAdd(&cur[d >> BUCK_SHIFT], 1);
        binned[q] = (d << 16) | s;
    }
}

__global__ __launch_bounds__(256) void k_reorder(const unsigned int* __restrict__ binned,
                                                 const int* __restrict__ scan,
                                                 unsigned short* __restrict__ adj,
                                                 int* __restrict__ offs,
                                                 float* __restrict__ dis,
                                                 int N, int nbuck, int M) {
    __shared__ int cnt[64];
    __shared__ int cur[64];
    __shared__ unsigned short stage[RCAP];
    int b = blockIdx.x;
    int start = scan[b * B1];
    int end = (b + 1 < nbuck) ? scan[(b + 1) * B1] : M;
    int len = end - start;
    if (threadIdx.x < 64) cnt[threadIdx.x] = 0;
    __syncthreads();
    for (int i = start + threadIdx.x; i < end; i += 256)
        atomicAdd(&cnt[(binned[i] >> 16) & 63], 1);
    __syncthreads();
    if (threadIdx.x == 0) {
        int run = 0;
        for (int l = 0; l < 64; ++l) { cur[l] = run; run += cnt[l]; }
    }
    __syncthreads();
    if (threadIdx.x < 64) {
        int node = (b << BUCK_SHIFT) + threadIdx.x;
        if (node < N) {
            offs[node] = start + cur[threadIdx.x];
            dis[node]  = rsqrtf(1.0f + (float)cnt[threadIdx.x]);
        }
    }
    __syncthreads();
    if (len <= RCAP) {
        for (int i = start + threadIdx.x; i < end; i += 256) {
            unsigned int v = binned[i];
            int nl = (v >> 16) & 63;
            int p = atomicAdd(&cur[nl], 1);
            stage[p] = (unsigned short)(v & 0xffffu);
        }
        __syncthreads();
        for (int i = threadIdx.x; i < len; i += 256)
            adj[start + i] = stage[i];
    } else {
        for (int i = start + threadIdx.x; i < end; i += 256) {
            unsigned int v = binned[i];
            int nl = (v >> 16) & 63;
            int p = atomicAdd(&cur[nl], 1);
            adj[start + p] = (unsigned short)(v & 0xffffu);
        }
    }
}

// ---------------------------------------------------------------------------
// GEMM1 via MFMA: hs_bf16[N][64] = bf16( (X@W1 + b1) * dis[row] ).
// Split-bf16 inputs: x = hi + lo; D = Ahi*Bhi + Alo*Bhi + Ahi*Blo.
// ---------------------------------------------------------------------------
#define WK 136  // padded K stride (ushorts)

__device__ __forceinline__ bf16x8 ld_frag(const unsigned short* p) {
    uint4 t = *reinterpret_cast<const uint4*>(p);
    Frag f; f.u[0] = t.x; f.u[1] = t.y; f.u[2] = t.z; f.u[3] = t.w;
    return f.v;
}

__device__ __forceinline__ void make_frags(const float4 a, const float4 b,
                                           bf16x8& hi8, bf16x8& lo8) {
    Frag hi, lo;
    hi.u[0] = cvt_pk_bf16(a.x, a.y);
    hi.u[1] = cvt_pk_bf16(a.z, a.w);
    hi.u[2] = cvt_pk_bf16(b.x, b.y);
    hi.u[3] = cvt_pk_bf16(b.z, b.w);
    lo.u[0] = cvt_pk_bf16(a.x - __uint_as_float(hi.u[0] << 16),
                          a.y - __uint_as_float(hi.u[0] & 0xffff0000u));
    lo.u[1] = cvt_pk_bf16(a.z - __uint_as_float(hi.u[1] << 16),
                          a.w - __uint_as_float(hi.u[1] & 0xffff0000u));
    lo.u[2] = cvt_pk_bf16(b.x - __uint_as_float(hi.u[2] << 16),
                          b.y - __uint_as_float(hi.u[2] & 0xffff0000u));
    lo.u[3] = cvt_pk_bf16(b.z - __uint_as_float(hi.u[3] << 16),
                          b.w - __uint_as_float(hi.u[3] & 0xffff0000u));
    hi8 = hi.v; lo8 = lo.v;
}

__global__ __launch_bounds__(256) void k_gemm1_mfma(const float* __restrict__ X,
                                                    const float* __restrict__ W1,
                                                    const float* __restrict__ b1,
                                                    const float* __restrict__ dis,
                                                    unsigned short* __restrict__ hsb,
                                                    int N) {
    __shared__ unsigned short sWhi[64 * WK];
    __shared__ unsigned short sWlo[64 * WK];
    for (int i = threadIdx.x; i < 128 * 64; i += 256) {
        int c = i >> 7;      // 0..63
        int k = i & 127;     // 0..127
        float w = W1[(size_t)k * 64 + c];
        unsigned int hb = cvt_pk_bf16(w, 0.0f) & 0xffffu;
        float hf = __uint_as_float(hb << 16);
        unsigned int lb = cvt_pk_bf16(w - hf, 0.0f) & 0xffffu;
        sWhi[c * WK + k] = (unsigned short)hb;
        sWlo[c * WK + k] = (unsigned short)lb;
    }
    __syncthreads();

    const int lane = threadIdx.x & 63;
    const int wid  = threadIdx.x >> 6;
    const int ridx = lane & 15;
    const int kgrp = lane >> 4;
    const int r0 = blockIdx.x * 128 + wid * 32;

    f32x4 acc[2][4] = {};

    #pragma unroll
    for (int ks = 0; ks < 4; ++ks) {
        const int ka = ks * 32 + kgrp * 8;
        int ra0 = min(r0 + ridx, N - 1);
        int ra1 = min(r0 + 16 + ridx, N - 1);
        const float4* pa0 = (const float4*)(X + (size_t)ra0 * 128 + ka);
        const float4* pa1 = (const float4*)(X + (size_t)ra1 * 128 + ka);
        float4 a0a = pa0[0], a0b = pa0[1];
        float4 a1a = pa1[0], a1b = pa1[1];
        bf16x8 a0hi, a0lo, a1hi, a1lo;
        make_frags(a0a, a0b, a0hi, a0lo);
        make_frags(a1a, a1b, a1hi, a1lo);
        #pragma unroll
        for (int ct = 0; ct < 4; ++ct) {
            const int cbase = (ct * 16 + ridx) * WK + ka;
            bf16x8 bh = ld_frag(sWhi + cbase);
            bf16x8 bl = ld_frag(sWlo + cbase);
            acc[0][ct] = __builtin_amdgcn_mfma_f32_16x16x32_bf16(a0hi, bh, acc[0][ct], 0, 0, 0);
            acc[0][ct] = __builtin_amdgcn_mfma_f32_16x16x32_bf16(a0lo, bh, acc[0][ct], 0, 0, 0);
            acc[0][ct] = __builtin_amdgcn_mfma_f32_16x16x32_bf16(a0hi, bl, acc[0][ct], 0, 0, 0);
            acc[1][ct] = __builtin_amdgcn_mfma_f32_16x16x32_bf16(a1hi, bh, acc[1][ct], 0, 0, 0);
            acc[1][ct] = __builtin_amdgcn_mfma_f32_16x16x32_bf16(a1lo, bh, acc[1][ct], 0, 0, 0);
            acc[1][ct] = __builtin_amdgcn_mfma_f32_16x16x32_bf16(a1hi, bl, acc[1][ct], 0, 0, 0);
        }
    }

    float bias[4];
    #pragma unroll
    for (int ct = 0; ct < 4; ++ct) bias[ct] = b1[ct * 16 + ridx];

    #pragma unroll
    for (int rt = 0; rt < 2; ++rt) {
        int rb = r0 + rt * 16 + kgrp * 4;
        #pragma unroll
        for (int reg = 0; reg < 4; ++reg) {
            int r = rb + reg;
            if (r < N) {
                float dv = dis[r];
                #pragma unroll
                for (int ct = 0; ct < 4; ++ct) {
                    float v = (acc[rt][ct][reg] + bias[ct]) * dv;
                    hsb[(size_t)r * 64 + ct * 16 + ridx] =
                        (unsigned short)(cvt_pk_bf16(v, 0.0f) & 0xffffu);
                }
            }
        }
    }
}

// out1[i][c] = relu(dis[i]*(hs[i][c] + sum_j hs[j][c])); wave per node.
// hs rows are bf16-packed (32 uints). Lanes 0-31 handle even neighbors,
// 32-63 odd; each lane covers channels (2*c2, 2*c2+1). Final shfl_xor merge.
__global__ __launch_bounds__(256) void k_gather64(const unsigned int* __restrict__ hsu,
                                                  const unsigned short* __restrict__ adj,
                                                  const int* __restrict__ offs,
                                                  const float* __restrict__ dis,
                                                  float* __restrict__ out, int N, int M) {
    int node = (blockIdx.x * 256 + threadIdx.x) >> 6;
    if (node >= N) return;
    int lane = threadIdx.x & 63;
    int half = lane >> 5;
    int c2 = lane & 31;
    int k   = offs[node];
    int end = (node + 1 < N) ? offs[node + 1] : M;
    float acc0 = 0.f, acc1 = 0.f;
    for (; k + 8 <= end; k += 8) {
        int j0 = adj[k + 0 + half];
        int j1 = adj[k + 2 + half];
        int j2 = adj[k + 4 + half];
        int j3 = adj[k + 6 + half];
        unsigned int u0 = hsu[(size_t)j0 * 32 + c2];
        unsigned int u1 = hsu[(size_t)j1 * 32 + c2];
        unsigned int u2 = hsu[(size_t)j2 * 32 + c2];
        unsigned int u3 = hsu[(size_t)j3 * 32 + c2];
        acc0 += (bf_lo(u0) + bf_lo(u1)) + (bf_lo(u2) + bf_lo(u3));
        acc1 += (bf_hi(u0) + bf_hi(u1)) + (bf_hi(u2) + bf_hi(u3));
    }
    for (; k + 2 <= end; k += 2) {
        int j = adj[k + half];
        unsigned int u = hsu[(size_t)j * 32 + c2];
        acc0 += bf_lo(u);
        acc1 += bf_hi(u);
    }
    if (k < end && half == 0) {
        int j = adj[k];
        unsigned int u = hsu[(size_t)j * 32 + c2];
        acc0 += bf_lo(u);
        acc1 += bf_hi(u);
    }
    acc0 += __shfl_xor(acc0, 32);
    acc1 += __shfl_xor(acc1, 32);
    unsigned int us = hsu[(size_t)node * 32 + c2];
    acc0 += bf_lo(us);
    acc1 += bf_hi(us);
    float d = dis[node];
    if (half == 0) {
        float2 r;
        r.x = fmaxf(d * acc0, 0.0f);
        r.y = fmaxf(d * acc1, 0.0f);
        *reinterpret_cast<float2*>(out + (size_t)node * 64 + 2 * c2) = r;
    }
}

// h2s_bf16[N][40] = bf16( (out1[N][64] @ W2[64][40] + b2) * dis[row] )
__global__ __launch_bounds__(256) void k_gemm2(const float* __restrict__ A,
                                               const float* __restrict__ W2,
                                               const float* __restrict__ b2,
                                               const float* __restrict__ dis,
                                               unsigned short* __restrict__ h2sb,
                                               int n40) {
    __shared__ float sW[64 * 40];
    __shared__ float sb[40];
    for (int i = threadIdx.x; i < 64 * 40; i += 256) sW[i] = W2[i];
    if (threadIdx.x < 40) sb[threadIdx.x] = b2[threadIdx.x];
    __syncthreads();
    int t = blockIdx.x * 256 + threadIdx.x;
    if (t >= n40) return;
    int row = t / 40;
    int col = t - row * 40;
    const float4* a = (const float4*)(A + (size_t)row * 64);
    float acc = sb[col];
    #pragma unroll
    for (int k4 = 0; k4 < 16; ++k4) {
        float4 v = a[k4];
        const float* w = &sW[k4 * 4 * 40 + col];
        acc += v.x * w[0] + v.y * w[40] + v.z * w[80] + v.w * w[120];
    }
    h2sb[t] = (unsigned short)(cvt_pk_bf16(acc * dis[row], 0.0f) & 0xffffu);
}

// out2[i][c] = dis[i]*(h2s[i][c] + sum_j h2s[j][c]); bf16 rows (20 uints).
__global__ __launch_bounds__(256) void k_gather40(const unsigned int* __restrict__ h2u,
                                                  const unsigned short* __restrict__ adj,
                                                  const int* __restrict__ offs,
                                                  const float* __restrict__ dis,
                                                  float* __restrict__ out, int N, int M) {
    int node = (blockIdx.x * 256 + threadIdx.x) >> 6;
    if (node >= N) return;
    int lane = threadIdx.x & 63;
    int half = lane >> 5;
    int c2 = lane & 31;
    bool act = c2 < 20;
    int k   = offs[node];
    int end = (node + 1 < N) ? offs[node + 1] : M;
    float acc0 = 0.f, acc1 = 0.f;
    for (; k + 8 <= end; k += 8) {
        int j0 = adj[k + 0 + half];
        int j1 = adj[k + 2 + half];
        int j2 = adj[k + 4 + half];
        int j3 = adj[k + 6 + half];
        if (act) {
            unsigned int u0 = h2u[(size_t)j0 * 20 + c2];
            unsigned int u1 = h2u[(size_t)j1 * 20 + c2];
            unsigned int u2 = h2u[(size_t)j2 * 20 + c2];
            unsigned int u3 = h2u[(size_t)j3 * 20 + c2];
            acc0 += (bf_lo(u0) + bf_lo(u1)) + (bf_lo(u2) + bf_lo(u3));
            acc1 += (bf_hi(u0) + bf_hi(u1)) + (bf_hi(u2) + bf_hi(u3));
        }
    }
    for (; k + 2 <= end; k += 2) {
        int j = adj[k + half];
        if (act) {
            unsigned int u = h2u[(size_t)j * 20 + c2];
            acc0 += bf_lo(u);
            acc1 += bf_hi(u);
        }
    }
    if (k < end && half == 0 && act) {
        int j = adj[k];
        unsigned int u = h2u[(size_t)j * 20 + c2];
        acc0 += bf_lo(u);
        acc1 += bf_hi(u);
    }
    acc0 += __shfl_xor(acc0, 32);
    acc1 += __shfl_xor(acc1, 32);
    if (half == 0 && act) {
        unsigned int us = h2u[(size_t)node * 20 + c2];
        float d = dis[node];
        float2 r;
        r.x = d * (acc0 + bf_lo(us));
        r.y = d * (acc1 + bf_hi(us));
        *reinterpret_cast<float2*>(out + (size_t)node * 40 + 2 * c2) = r;
    }
}

extern "C" void kernel_launch(void* const* d_in, const int* in_sizes, int n_in,
                              void* d_out, int out_size, void* d_ws, size_t ws_size,
                              hipStream_t stream) {
    const float* X  = (const float*)d_in[0];
    const float* W1 = (const float*)d_in[1];
    const float* b1 = (const float*)d_in[2];
    const float* W2 = (const float*)d_in[3];
    const float* b2 = (const float*)d_in[4];
    const int*   ei = (const int*)d_in[5];

    const int Chid = in_sizes[2];            // 64
    const int Cin  = in_sizes[1] / Chid;     // 128
    const int N    = in_sizes[0] / Cin;      // 50000
    const int E    = in_sizes[5] / 2;        // 800000

    const int* src = ei;
    const int* dst = ei + E;

    const int M = 2 * E;                        // 1.6M entries
    const int nbuck = (N + 63) >> BUCK_SHIFT;   // 782
    const int histLen = nbuck * B1;             // 200192
    const int chunk = (E + B1 - 1) / B1;        // 3125
    const int nb2 = (histLen + 255) / 256;      // 782

    // ---- workspace layout (binned dead after reorder; hs overlays it)
    auto align256 = [](size_t x) { return (x + 255) & ~(size_t)255; };
    char* p = (char*)d_ws;
    int*   hist = (int*)p;   p += align256((size_t)histLen * 4);
    int*   bsum = (int*)p;   p += align256((size_t)nb2 * 4);
    float* dis  = (float*)p; p += align256((size_t)N * 4);
    int*   offs = (int*)p;   p += align256((size_t)N * 4);
    unsigned short* adj = (unsigned short*)p; p += align256((size_t)M * 2);
    unsigned int* binned = (unsigned int*)p;        // M uints (6.4MB) ...
    unsigned short* hsb = (unsigned short*)p;        // ... reused: N*64 bf16
    unsigned short* h2sb = hsb;                      // reused again: N*40 bf16

    float* out1 = (float*)d_out;             // N*64
    float* out2 = out1 + (size_t)N * 64;     // N*40

    k_hist<<<B1, 256, 0, stream>>>(src, dst, hist, E, nbuck, chunk);
    k_block_sum<<<nb2, 256, 0, stream>>>(hist, bsum, histLen);
    k_scan_single<<<1, 1024, 0, stream>>>(bsum, nb2);
    k_scan_block<<<nb2, 256, 0, stream>>>(hist, bsum, histLen);
    k_scatter<<<B1, 256, 0, stream>>>(src, dst, hist, binned, E, nbuck, chunk);
    k_reorder<<<nbuck, 256, 0, stream>>>(binned, hist, adj, offs, dis, N, nbuck, M);

    k_gemm1_mfma<<<(N + 127) / 128, 256, 0, stream>>>(X, W1, b1, dis, hsb, N);
    k_gather64<<<(N + 3) / 4, 256, 0, stream>>>((const unsigned int*)hsb, adj, offs,
                                                dis, out1, N, M);

    int n40 = N * 40;
    k_gemm2<<<(n40 + 255) / 256, 256, 0, stream>>>(out1, W2, b2, dis, h2sb, n40);
    k_gather40<<<(N + 3) / 4, 256, 0, stream>>>((const unsigned int*)h2sb, adj, offs,
                                                dis, out2, N, M);
}